// Round 2
// baseline (1566.885 us; speedup 1.0000x reference)
//
#include <hip/hip_runtime.h>
#include <math.h>

// RelationMessagePassing fp32 baseline.
//
// Pipeline (all on `stream`):
//   0. memset ws: gmax (ordered-uint, 0 == "-inf") + exps_sum[N*64] = 0
//   1. rel_kernel<64/128/192>: gather -> MLP -> atomicMax(global max of msgs)
//      + atomicAdd(exp(8*msg)) into exps_sum   [single pass; offset applied later]
//   2. up_kernel: max_msg = log(1e-16 + S*exp(-8M))/8 + M ; concat with states;
//      128->128 relu ->64 MLP; write d_out.
//
// Identity used: log(1e-16 + sum exp(8(o-M)))/8 + M == log(1e-16 + (sum exp(8o))*e^(-8M))/8 + M
// so accumulating exp(8*o) directly is exact-to-rounding, incl. degree-0 nodes.

#define TBROWS 64

__device__ __forceinline__ unsigned f2ord(float f) {
    unsigned u = __float_as_uint(f);
    return (u & 0x80000000u) ? ~u : (u | 0x80000000u);
}
__device__ __forceinline__ float ord2f(unsigned u) {
    return (u & 0x80000000u) ? __uint_as_float(u & 0x7fffffffu) : __uint_as_float(~u);
}

// D = arity*64. One block = 64 tuples. 4 waves; each wave owns 16 rows.
template <int D>
__global__ __launch_bounds__(256) void rel_kernel(
    const float* __restrict__ states, const int* __restrict__ idx,
    const float* __restrict__ W1, const float* __restrict__ B1,
    const float* __restrict__ W2, const float* __restrict__ B2,
    float* __restrict__ exps, unsigned* __restrict__ gmax, int E) {
    constexpr int A = D / 64;
    constexpr int G = A;
    __shared__ float Xs[TBROWS * D];   // X tile, later overwritten by H (per-wave rows)
    __shared__ int Ids[TBROWS * A];

    const int tid = threadIdx.x;
    const int block0 = blockIdx.x * TBROWS;
    const int validRows = min(TBROWS, E - block0);
    const int validSegs = validRows * A;
    const long long segBase = (long long)block0 * A;

    // ---- gather: segment s (= row*A + slot) -> Xs[s*64 .. s*64+63]
    for (int q = tid; q < TBROWS * A * 16; q += 256) {
        int s = q >> 4;
        int f = q & 15;
        float4 v = make_float4(0.f, 0.f, 0.f, 0.f);
        if (s < validSegs) {
            int node = idx[segBase + s];
            v = *reinterpret_cast<const float4*>(states + (long long)node * 64 + f * 4);
            if (f == 0) Ids[s] = node;
        }
        reinterpret_cast<float4*>(Xs)[q] = v;
    }
    __syncthreads();

    const int w = tid >> 6;
    const int c = tid & 63;
    const int row0 = w * 16;

    float acc[16][G];

    // ---- layer 1: h = relu(x @ W1 + b1)
    #pragma unroll
    for (int g = 0; g < G; ++g) {
        float b = B1[c + 64 * g];
        #pragma unroll
        for (int r = 0; r < 16; ++r) acc[r][g] = b;
    }
    for (int k = 0; k < D; k += 4) {
        float4 wv[G];
        #pragma unroll
        for (int g = 0; g < G; ++g) {
            wv[g].x = W1[(k + 0) * D + c + 64 * g];
            wv[g].y = W1[(k + 1) * D + c + 64 * g];
            wv[g].z = W1[(k + 2) * D + c + 64 * g];
            wv[g].w = W1[(k + 3) * D + c + 64 * g];
        }
        #pragma unroll
        for (int r = 0; r < 16; ++r) {
            float4 xv = *reinterpret_cast<const float4*>(&Xs[(row0 + r) * D + k]);
            #pragma unroll
            for (int g = 0; g < G; ++g) {
                acc[r][g] = fmaf(xv.x, wv[g].x, acc[r][g]);
                acc[r][g] = fmaf(xv.y, wv[g].y, acc[r][g]);
                acc[r][g] = fmaf(xv.z, wv[g].z, acc[r][g]);
                acc[r][g] = fmaf(xv.w, wv[g].w, acc[r][g]);
            }
        }
    }
    // relu, write H into this wave's own Xs rows (no cross-wave readers -> no barrier)
    #pragma unroll
    for (int r = 0; r < 16; ++r)
        #pragma unroll
        for (int g = 0; g < G; ++g)
            Xs[(row0 + r) * D + c + 64 * g] = fmaxf(acc[r][g], 0.f);

    // ---- layer 2: o = h @ W2 + b2
    #pragma unroll
    for (int g = 0; g < G; ++g) {
        float b = B2[c + 64 * g];
        #pragma unroll
        for (int r = 0; r < 16; ++r) acc[r][g] = b;
    }
    for (int k = 0; k < D; k += 4) {
        float4 wv[G];
        #pragma unroll
        for (int g = 0; g < G; ++g) {
            wv[g].x = W2[(k + 0) * D + c + 64 * g];
            wv[g].y = W2[(k + 1) * D + c + 64 * g];
            wv[g].z = W2[(k + 2) * D + c + 64 * g];
            wv[g].w = W2[(k + 3) * D + c + 64 * g];
        }
        #pragma unroll
        for (int r = 0; r < 16; ++r) {
            float4 xv = *reinterpret_cast<const float4*>(&Xs[(row0 + r) * D + k]);
            #pragma unroll
            for (int g = 0; g < G; ++g) {
                acc[r][g] = fmaf(xv.x, wv[g].x, acc[r][g]);
                acc[r][g] = fmaf(xv.y, wv[g].y, acc[r][g]);
                acc[r][g] = fmaf(xv.z, wv[g].z, acc[r][g]);
                acc[r][g] = fmaf(xv.w, wv[g].w, acc[r][g]);
            }
        }
    }

    // ---- epilogue: global max + exp(8*o) scatter-accumulate
    const int rv = min(16, validRows - row0);
    if (rv > 0) {
        float m = -INFINITY;
        for (int r = 0; r < rv; ++r)
            #pragma unroll
            for (int g = 0; g < G; ++g) m = fmaxf(m, acc[r][g]);
        #pragma unroll
        for (int off = 32; off > 0; off >>= 1) m = fmaxf(m, __shfl_xor(m, off));
        if (c == 0) atomicMax(gmax, f2ord(m));

        for (int r = 0; r < rv; ++r) {
            #pragma unroll
            for (int g = 0; g < G; ++g) {
                int node = Ids[(row0 + r) * A + g];
                atomicAdd(&exps[(long long)node * 64 + c], __expf(8.f * acc[r][g]));
            }
        }
    }
}

// Final: max_msg + concat + up-MLP (128 -> 128 relu -> 64)
__global__ __launch_bounds__(256) void up_kernel(
    const float* __restrict__ states, const float* __restrict__ exps,
    const unsigned* __restrict__ gmaxp,
    const float* __restrict__ W1, const float* __restrict__ B1,
    const float* __restrict__ W2, const float* __restrict__ B2,
    float* __restrict__ outp, int Nn) {
    constexpr int D = 128;
    __shared__ float Xs[TBROWS * D];
    const int tid = threadIdx.x;
    const int block0 = blockIdx.x * TBROWS;
    const int validRows = min(TBROWS, Nn - block0);
    const float M = ord2f(*gmaxp);
    const float EM = __expf(-8.f * M);

    // build X tile: cols 0..63 = max_msg, 64..127 = node_states
    for (int q = tid; q < TBROWS * 32; q += 256) {
        int r = q >> 5;
        int f = q & 31;
        float4 v = make_float4(0.f, 0.f, 0.f, 0.f);
        if (r < validRows) {
            long long n = (long long)(block0 + r);
            if (f < 16) {
                float4 s4 = *reinterpret_cast<const float4*>(exps + n * 64 + f * 4);
                v.x = __logf(1e-16f + s4.x * EM) * 0.125f + M;
                v.y = __logf(1e-16f + s4.y * EM) * 0.125f + M;
                v.z = __logf(1e-16f + s4.z * EM) * 0.125f + M;
                v.w = __logf(1e-16f + s4.w * EM) * 0.125f + M;
            } else {
                v = *reinterpret_cast<const float4*>(states + n * 64 + (f - 16) * 4);
            }
        }
        reinterpret_cast<float4*>(Xs)[q] = v;
    }
    __syncthreads();

    const int w = tid >> 6;
    const int c = tid & 63;
    const int row0 = w * 16;

    // layer 1 (128 -> 128)
    float acc[16][2];
    #pragma unroll
    for (int g = 0; g < 2; ++g) {
        float b = B1[c + 64 * g];
        #pragma unroll
        for (int r = 0; r < 16; ++r) acc[r][g] = b;
    }
    for (int k = 0; k < D; k += 4) {
        float4 wv[2];
        #pragma unroll
        for (int g = 0; g < 2; ++g) {
            wv[g].x = W1[(k + 0) * D + c + 64 * g];
            wv[g].y = W1[(k + 1) * D + c + 64 * g];
            wv[g].z = W1[(k + 2) * D + c + 64 * g];
            wv[g].w = W1[(k + 3) * D + c + 64 * g];
        }
        #pragma unroll
        for (int r = 0; r < 16; ++r) {
            float4 xv = *reinterpret_cast<const float4*>(&Xs[(row0 + r) * D + k]);
            #pragma unroll
            for (int g = 0; g < 2; ++g) {
                acc[r][g] = fmaf(xv.x, wv[g].x, acc[r][g]);
                acc[r][g] = fmaf(xv.y, wv[g].y, acc[r][g]);
                acc[r][g] = fmaf(xv.z, wv[g].z, acc[r][g]);
                acc[r][g] = fmaf(xv.w, wv[g].w, acc[r][g]);
            }
        }
    }
    #pragma unroll
    for (int r = 0; r < 16; ++r)
        #pragma unroll
        for (int g = 0; g < 2; ++g)
            Xs[(row0 + r) * D + c + 64 * g] = fmaxf(acc[r][g], 0.f);

    // layer 2 (128 -> 64)
    float o[16];
    {
        float b = B2[c];
        #pragma unroll
        for (int r = 0; r < 16; ++r) o[r] = b;
    }
    for (int k = 0; k < D; k += 4) {
        float4 wv;
        wv.x = W2[(k + 0) * 64 + c];
        wv.y = W2[(k + 1) * 64 + c];
        wv.z = W2[(k + 2) * 64 + c];
        wv.w = W2[(k + 3) * 64 + c];
        #pragma unroll
        for (int r = 0; r < 16; ++r) {
            float4 xv = *reinterpret_cast<const float4*>(&Xs[(row0 + r) * D + k]);
            o[r] = fmaf(xv.x, wv.x, o[r]);
            o[r] = fmaf(xv.y, wv.y, o[r]);
            o[r] = fmaf(xv.z, wv.z, o[r]);
            o[r] = fmaf(xv.w, wv.w, o[r]);
        }
    }
    const int rv = min(16, validRows - row0);
    for (int r = 0; r < rv; ++r)
        outp[(long long)(block0 + row0 + r) * 64 + c] = o[r];
}

extern "C" void kernel_launch(void* const* d_in, const int* in_sizes, int n_in,
                              void* d_out, int out_size, void* d_ws, size_t ws_size,
                              hipStream_t stream) {
    const float* states = (const float*)d_in[0];
    const int* idx0 = (const int*)d_in[1];
    const int* idx1 = (const int*)d_in[2];
    const int* idx2 = (const int*)d_in[3];
    const float* r0w1 = (const float*)d_in[4];
    const float* r0b1 = (const float*)d_in[5];
    const float* r0w2 = (const float*)d_in[6];
    const float* r0b2 = (const float*)d_in[7];
    const float* r1w1 = (const float*)d_in[8];
    const float* r1b1 = (const float*)d_in[9];
    const float* r1w2 = (const float*)d_in[10];
    const float* r1b2 = (const float*)d_in[11];
    const float* r2w1 = (const float*)d_in[12];
    const float* r2b1 = (const float*)d_in[13];
    const float* r2w2 = (const float*)d_in[14];
    const float* r2b2 = (const float*)d_in[15];
    const float* upw1 = (const float*)d_in[16];
    const float* upb1 = (const float*)d_in[17];
    const float* upw2 = (const float*)d_in[18];
    const float* upb2 = (const float*)d_in[19];

    const int N = in_sizes[0] / 64;
    const int E0 = in_sizes[1] / 1;
    const int E1 = in_sizes[2] / 2;
    const int E2 = in_sizes[3] / 3;

    unsigned* gmax = (unsigned*)d_ws;
    float* exps = (float*)((char*)d_ws + 256);

    // zero gmax (ordered-uint 0 acts as -inf) and exps_sum; deterministic per launch
    hipMemsetAsync(d_ws, 0, 256 + (size_t)N * 64 * sizeof(float), stream);

    rel_kernel<64><<<dim3((E0 + TBROWS - 1) / TBROWS), dim3(256), 0, stream>>>(
        states, idx0, r0w1, r0b1, r0w2, r0b2, exps, gmax, E0);
    rel_kernel<128><<<dim3((E1 + TBROWS - 1) / TBROWS), dim3(256), 0, stream>>>(
        states, idx1, r1w1, r1b1, r1w2, r1b2, exps, gmax, E1);
    rel_kernel<192><<<dim3((E2 + TBROWS - 1) / TBROWS), dim3(256), 0, stream>>>(
        states, idx2, r2w1, r2b1, r2w2, r2b2, exps, gmax, E2);
    up_kernel<<<dim3((N + TBROWS - 1) / TBROWS), dim3(256), 0, stream>>>(
        states, exps, gmax, upw1, upb1, upw2, upb2, (float*)d_out, N);
}

// Round 3
// 1186.731 us; speedup vs baseline: 1.3203x; 1.3203x over previous
//
#include <hip/hip_runtime.h>
#include <math.h>

// RelationMessagePassing — bf16 MFMA version.
//
//   0. memset ws: gmax + exps_sum[N*64]=0
//   1. prep: states->bf16 copy; 8 weight mats -> transposed bf16 Wt[n][k]
//   2. rel_mfma<64/128/192>: gather bf16 -> MFMA MLP (fp32 acc) ->
//      atomicMax(global max) + atomicAdd(exp(8*msg)) into exps_sum
//   3. up_mfma: max_msg = log(1e-16+S*e^-8M)/8+M; concat; MFMA up-MLP; store fp32
//
// MFMA 16x16x32 bf16; A-frag: row=l&15, k=(l>>4)*8+j (LDS, XOR-swizzled);
// B-frag: col=l&15, same k (global, transposed weights => 16B contiguous);
// C/D: col=l&15, row=(l>>4)*4+reg  [m89-verified layout].
// LDS XOR swizzle: byte ^= (row&7)<<4 kills the stride-128/256/384B same-bank
// conflict on ds_read_b128 A-frags (guide G4).
//
// ws layout: [0,256) gmax | exps fp32 N*64 | states bf16 N*64 | 8 Wt bf16 (~39MB total)

typedef __attribute__((ext_vector_type(8))) short bf16x8;
typedef __attribute__((ext_vector_type(4))) float f32x4;
typedef unsigned short u16;

__device__ __forceinline__ unsigned f2ord(float f) {
    unsigned u = __float_as_uint(f);
    return (u & 0x80000000u) ? ~u : (u | 0x80000000u);
}
__device__ __forceinline__ float ord2f(unsigned u) {
    return (u & 0x80000000u) ? __uint_as_float(u & 0x7fffffffu) : __uint_as_float(~u);
}
__device__ __forceinline__ u16 f2bf(float f) {   // RNE f32->bf16 (finite inputs)
    unsigned u = __float_as_uint(f);
    return (u16)((u + 0x7fffu + ((u >> 16) & 1u)) >> 16);
}

// ---------------- prep ----------------
__global__ __launch_bounds__(256) void conv_states(const float* __restrict__ src,
                                                   u16* __restrict__ dst, int n8) {
    int i = blockIdx.x * 256 + threadIdx.x;
    if (i >= n8) return;
    float4 a = reinterpret_cast<const float4*>(src)[2 * i];
    float4 b = reinterpret_cast<const float4*>(src)[2 * i + 1];
    bf16x8 v;
    v[0] = (short)f2bf(a.x); v[1] = (short)f2bf(a.y);
    v[2] = (short)f2bf(a.z); v[3] = (short)f2bf(a.w);
    v[4] = (short)f2bf(b.x); v[5] = (short)f2bf(b.y);
    v[6] = (short)f2bf(b.z); v[7] = (short)f2bf(b.w);
    reinterpret_cast<bf16x8*>(dst)[i] = v;
}

struct TEnt { const float* src; u16* dst; int K, N, base; };
struct TPack { TEnt e[8]; };
// dst[n*K + k] = bf16(src[k*N + n])
__global__ __launch_bounds__(256) void transpose_w(TPack p) {
    int b = blockIdx.x;
    int i = 0;
    while (i < 7 && b >= p.e[i + 1].base) ++i;
    TEnt e = p.e[i];
    int idx = (b - e.base) * 256 + threadIdx.x;
    if (idx < e.K * e.N) {
        int n = idx / e.K, k = idx - n * e.K;
        e.dst[idx] = f2bf(e.src[k * e.N + n]);
    }
}

// ---------------- relation kernels ----------------
template <int D>
__global__ __launch_bounds__(256) void rel_mfma(
    const u16* __restrict__ statesb, const int* __restrict__ idx,
    const u16* __restrict__ W1t, const float* __restrict__ B1,
    const u16* __restrict__ W2t, const float* __restrict__ B2,
    float* __restrict__ exps, unsigned* __restrict__ gmax, int E) {
    constexpr int A = D / 64;
    constexpr int NF = D / 16;
    constexpr int KF = D / 32;
    __shared__ __align__(16) u16 Xs[64 * D];
    __shared__ int Ids[64 * A];
    char* Xc = (char*)Xs;

    const int tid = threadIdx.x;
    const int block0 = blockIdx.x * 64;
    const int validRows = min(64, E - block0);
    const int validSegs = validRows * A;
    const long long segBase = (long long)block0 * A;

    // gather: seg s -> row s/A, cols (s%A)*64.. ; 8 chunks of 16B per seg
    for (int q = tid; q < 64 * A * 8; q += 256) {
        int s = q >> 3, j = q & 7;
        int r = s / A, slot = s - r * A;
        bf16x8 v = {};
        if (s < validSegs) {
            int node = idx[segBase + s];
            v = *reinterpret_cast<const bf16x8*>(statesb + (long long)node * 64 + j * 8);
            if (j == 0) Ids[s] = node;
        }
        int byte = (slot * 128 + j * 16) ^ ((r & 7) << 4);
        *reinterpret_cast<bf16x8*>(Xc + r * (2 * D) + byte) = v;
    }
    __syncthreads();

    const int l = tid & 63;
    const int ln = l & 15, kq = l >> 4;
    const int row0 = (tid >> 6) * 16;

    f32x4 acc[NF];
    // ---- layer 1
    #pragma unroll
    for (int n = 0; n < NF; ++n) {
        float b = B1[n * 16 + ln];
        acc[n] = {b, b, b, b};
    }
    {
        const u16* wb = W1t + ln * D + kq * 8;
        #pragma unroll
        for (int kf = 0; kf < KF; ++kf) {
            bf16x8 a = *reinterpret_cast<const bf16x8*>(
                Xc + (row0 + ln) * (2 * D) + ((kf * 64 + kq * 16) ^ ((ln & 7) << 4)));
            #pragma unroll
            for (int n = 0; n < NF; ++n) {
                bf16x8 b = *reinterpret_cast<const bf16x8*>(wb + n * 16 * D + kf * 32);
                acc[n] = __builtin_amdgcn_mfma_f32_16x16x32_bf16(a, b, acc[n], 0, 0, 0);
            }
        }
    }
    // relu -> H in own 16 rows (wave-local; no barrier needed)
    #pragma unroll
    for (int n = 0; n < NF; ++n) {
        #pragma unroll
        for (int j = 0; j < 4; ++j) {
            int rl = kq * 4 + j;
            int byte = ((n * 16 + ln) * 2) ^ ((rl & 7) << 4);
            *reinterpret_cast<u16*>(Xc + (row0 + rl) * (2 * D) + byte) =
                f2bf(fmaxf(acc[n][j], 0.f));
        }
    }
    // ---- layer 2
    #pragma unroll
    for (int n = 0; n < NF; ++n) {
        float b = B2[n * 16 + ln];
        acc[n] = {b, b, b, b};
    }
    {
        const u16* wb = W2t + ln * D + kq * 8;
        #pragma unroll
        for (int kf = 0; kf < KF; ++kf) {
            bf16x8 a = *reinterpret_cast<const bf16x8*>(
                Xc + (row0 + ln) * (2 * D) + ((kf * 64 + kq * 16) ^ ((ln & 7) << 4)));
            #pragma unroll
            for (int n = 0; n < NF; ++n) {
                bf16x8 b = *reinterpret_cast<const bf16x8*>(wb + n * 16 * D + kf * 32);
                acc[n] = __builtin_amdgcn_mfma_f32_16x16x32_bf16(a, b, acc[n], 0, 0, 0);
            }
        }
    }
    // ---- epilogue: global max + exp(8*o) scatter
    float m = -INFINITY;
    #pragma unroll
    for (int n = 0; n < NF; ++n)
        #pragma unroll
        for (int j = 0; j < 4; ++j) {
            int row = row0 + kq * 4 + j;
            if (row < validRows) m = fmaxf(m, acc[n][j]);
        }
    #pragma unroll
    for (int off = 32; off; off >>= 1) m = fmaxf(m, __shfl_xor(m, off));
    if (l == 0) atomicMax(gmax, f2ord(m));

    #pragma unroll
    for (int n = 0; n < NF; ++n) {
        const int slot = n >> 2;
        const int feat = (n * 16 + ln) & 63;
        #pragma unroll
        for (int j = 0; j < 4; ++j) {
            int row = row0 + kq * 4 + j;
            if (row < validRows) {
                int node = Ids[row * A + slot];
                atomicAdd(exps + (long long)node * 64 + feat, __expf(8.f * acc[n][j]));
            }
        }
    }
}

// ---------------- up kernel ----------------
__global__ __launch_bounds__(256) void up_mfma(
    const u16* __restrict__ statesb, const float* __restrict__ exps,
    const unsigned* __restrict__ gmaxp,
    const u16* __restrict__ W1t, const float* __restrict__ B1,
    const u16* __restrict__ W2t, const float* __restrict__ B2,
    float* __restrict__ outp, int Nn) {
    constexpr int D = 128;
    __shared__ __align__(16) u16 Xs[64 * D];
    char* Xc = (char*)Xs;
    const int tid = threadIdx.x;
    const int block0 = blockIdx.x * 64;
    const int validRows = min(64, Nn - block0);
    const float M = ord2f(*gmaxp);
    const float EM = __expf(-8.f * M);

    // X tile: cols 0..63 = max_msg, 64..127 = states
    for (int q = tid; q < 64 * 16; q += 256) {
        int r = q >> 4, p = q & 15;
        bf16x8 v = {};
        if (r < validRows) {
            long long nd = block0 + r;
            if (p < 8) {
                float4 s0 = *reinterpret_cast<const float4*>(exps + nd * 64 + p * 8);
                float4 s1 = *reinterpret_cast<const float4*>(exps + nd * 64 + p * 8 + 4);
                float t[8] = {s0.x, s0.y, s0.z, s0.w, s1.x, s1.y, s1.z, s1.w};
                #pragma unroll
                for (int i = 0; i < 8; ++i)
                    v[i] = (short)f2bf(__logf(1e-16f + t[i] * EM) * 0.125f + M);
            } else {
                v = *reinterpret_cast<const bf16x8*>(statesb + nd * 64 + (p - 8) * 8);
            }
        }
        int byte = (p * 16) ^ ((r & 7) << 4);
        *reinterpret_cast<bf16x8*>(Xc + r * 256 + byte) = v;
    }
    __syncthreads();

    const int l = tid & 63;
    const int ln = l & 15, kq = l >> 4;
    const int row0 = (tid >> 6) * 16;

    // layer 1: 128 -> 128
    f32x4 acc[8];
    #pragma unroll
    for (int n = 0; n < 8; ++n) {
        float b = B1[n * 16 + ln];
        acc[n] = {b, b, b, b};
    }
    {
        const u16* wb = W1t + ln * D + kq * 8;
        #pragma unroll
        for (int kf = 0; kf < 4; ++kf) {
            bf16x8 a = *reinterpret_cast<const bf16x8*>(
                Xc + (row0 + ln) * 256 + ((kf * 64 + kq * 16) ^ ((ln & 7) << 4)));
            #pragma unroll
            for (int n = 0; n < 8; ++n) {
                bf16x8 b = *reinterpret_cast<const bf16x8*>(wb + n * 16 * D + kf * 32);
                acc[n] = __builtin_amdgcn_mfma_f32_16x16x32_bf16(a, b, acc[n], 0, 0, 0);
            }
        }
    }
    #pragma unroll
    for (int n = 0; n < 8; ++n) {
        #pragma unroll
        for (int j = 0; j < 4; ++j) {
            int rl = kq * 4 + j;
            int byte = ((n * 16 + ln) * 2) ^ ((rl & 7) << 4);
            *reinterpret_cast<u16*>(Xc + (row0 + rl) * 256 + byte) =
                f2bf(fmaxf(acc[n][j], 0.f));
        }
    }
    // layer 2: 128 -> 64
    f32x4 acc2[4];
    #pragma unroll
    for (int n = 0; n < 4; ++n) {
        float b = B2[n * 16 + ln];
        acc2[n] = {b, b, b, b};
    }
    {
        const u16* wb = W2t + ln * D + kq * 8;   // W2t is [64][128]
        #pragma unroll
        for (int kf = 0; kf < 4; ++kf) {
            bf16x8 a = *reinterpret_cast<const bf16x8*>(
                Xc + (row0 + ln) * 256 + ((kf * 64 + kq * 16) ^ ((ln & 7) << 4)));
            #pragma unroll
            for (int n = 0; n < 4; ++n) {
                bf16x8 b = *reinterpret_cast<const bf16x8*>(wb + n * 16 * D + kf * 32);
                acc2[n] = __builtin_amdgcn_mfma_f32_16x16x32_bf16(a, b, acc2[n], 0, 0, 0);
            }
        }
    }
    #pragma unroll
    for (int n = 0; n < 4; ++n)
        #pragma unroll
        for (int j = 0; j < 4; ++j) {
            int row = row0 + kq * 4 + j;
            if (row < validRows)
                outp[(long long)(block0 + row) * 64 + n * 16 + ln] = acc2[n][j];
        }
}

extern "C" void kernel_launch(void* const* d_in, const int* in_sizes, int n_in,
                              void* d_out, int out_size, void* d_ws, size_t ws_size,
                              hipStream_t stream) {
    const float* states = (const float*)d_in[0];
    const int* idx0 = (const int*)d_in[1];
    const int* idx1 = (const int*)d_in[2];
    const int* idx2 = (const int*)d_in[3];
    const float* rw1[3] = {(const float*)d_in[4], (const float*)d_in[8], (const float*)d_in[12]};
    const float* rb1[3] = {(const float*)d_in[5], (const float*)d_in[9], (const float*)d_in[13]};
    const float* rw2[3] = {(const float*)d_in[6], (const float*)d_in[10], (const float*)d_in[14]};
    const float* rb2[3] = {(const float*)d_in[7], (const float*)d_in[11], (const float*)d_in[15]};
    const float* upw1 = (const float*)d_in[16];
    const float* upb1 = (const float*)d_in[17];
    const float* upw2 = (const float*)d_in[18];
    const float* upb2 = (const float*)d_in[19];

    const int N = in_sizes[0] / 64;
    const int E0 = in_sizes[1] / 1;
    const int E1 = in_sizes[2] / 2;
    const int E2 = in_sizes[3] / 3;

    size_t off = 0;
    auto alloc = [&](size_t bytes) {
        void* p = (char*)d_ws + off;
        off += (bytes + 255) & ~(size_t)255;
        return p;
    };
    unsigned* gmax = (unsigned*)alloc(4);
    float* exps = (float*)alloc((size_t)N * 64 * 4);
    u16* statesb = (u16*)alloc((size_t)N * 64 * 2);
    u16* w1t[3], *w2t[3];
    const int Dd[3] = {64, 128, 192};
    for (int r = 0; r < 3; ++r) {
        w1t[r] = (u16*)alloc((size_t)Dd[r] * Dd[r] * 2);
        w2t[r] = (u16*)alloc((size_t)Dd[r] * Dd[r] * 2);
    }
    u16* upw1t = (u16*)alloc(128 * 128 * 2);
    u16* upw2t = (u16*)alloc(64 * 128 * 2);

    // zero gmax (ordered-uint 0 == -inf) + exps
    hipMemsetAsync(d_ws, 0, 256 + (size_t)N * 64 * 4, stream);

    conv_states<<<dim3((N * 64 / 8 + 255) / 256), dim3(256), 0, stream>>>(
        states, statesb, N * 64 / 8);

    TPack tp;
    const float* tsrc[8] = {rw1[0], rw2[0], rw1[1], rw2[1], rw1[2], rw2[2], upw1, upw2};
    u16* tdst[8] = {w1t[0], w2t[0], w1t[1], w2t[1], w1t[2], w2t[2], upw1t, upw2t};
    const int tK[8] = {64, 64, 128, 128, 192, 192, 128, 128};
    const int tN[8] = {64, 64, 128, 128, 192, 192, 128, 64};
    int base = 0;
    for (int i = 0; i < 8; ++i) {
        tp.e[i] = {tsrc[i], tdst[i], tK[i], tN[i], base};
        base += (tK[i] * tN[i] + 255) / 256;
    }
    transpose_w<<<dim3(base), dim3(256), 0, stream>>>(tp);

    rel_mfma<64><<<dim3((E0 + 63) / 64), dim3(256), 0, stream>>>(
        statesb, idx0, w1t[0], rb1[0], w2t[0], rb2[0], exps, gmax, E0);
    rel_mfma<128><<<dim3((E1 + 63) / 64), dim3(256), 0, stream>>>(
        statesb, idx1, w1t[1], rb1[1], w2t[1], rb2[1], exps, gmax, E1);
    rel_mfma<192><<<dim3((E2 + 63) / 64), dim3(256), 0, stream>>>(
        statesb, idx2, w1t[2], rb1[2], w2t[2], rb2[2], exps, gmax, E2);
    up_mfma<<<dim3((N + 63) / 64), dim3(256), 0, stream>>>(
        statesb, exps, gmax, upw1t, upb1, upw2t, upb2, (float*)d_out, N);
}